// Round 6
// baseline (510.737 us; speedup 1.0000x reference)
//
#include <hip/hip_runtime.h>
#include <math.h>

constexpr int An = 3;
constexpr int Wd = 52;
constexpr int HWn = 2704;        // 52*52
constexpr int ATT = 85;
constexpr int CH = 208;          // 4 grid rows per decode tile
constexpr int PITCH = 209;       // odd -> bank stride 17, conflict-free both phases
constexpr int CHUNKS = 13;       // 2704 / 208
constexpr int DEC_BLOCKS = 96 * CHUNKS;    // 1248
constexpr int NC = An * HWn;     // 8112 candidates (batch 0)
constexpr int OUT_DEC = 32 * NC * ATT;     // 22064640 floats (decode output)
constexpr int WS_SCORE_OFF = 65536;
constexpr size_t DEC_LDS = (size_t)ATT * PITCH * sizeof(float);   // 71,060 B

__device__ __forceinline__ float sig_precise(float x) {   // scoring path
    return 1.0f / (1.0f + expf(-x));
}
__device__ __forceinline__ float sig_fast(float x) {      // decode path, loose tol
    return 1.0f / (1.0f + __expf(-x));
}

// ==================== kernel 1: prep (candidate scoring, batch 0) ====================
__global__ void __launch_bounds__(128)
yolo_prep(const float* __restrict__ in, const float* __restrict__ anc,
          float* __restrict__ ws)
{
    const int n = blockIdx.x * 128 + threadIdx.x;
    if (n >= NC) return;
    const int a   = n / HWn;
    const int pos = n - a * HWn;
    const float* p = in + (size_t)a * 85 * HWn + pos;

    const float tx = p[0];
    const float ty = p[HWn];
    const float tw = p[2 * HWn];
    const float th = p[3 * HWn];
    const float tc = p[4 * HWn];

    float m = -3.0e38f; int cp = 0;
    #pragma unroll
    for (int j0 = 0; j0 < 80; j0 += 16) {
        float v[16];
        #pragma unroll
        for (int u = 0; u < 16; ++u) v[u] = p[(size_t)(5 + j0 + u) * HWn];
        #pragma unroll
        for (int u = 0; u < 16; ++u) {
            if (v[u] > m) { m = v[u]; cp = j0 + u; }
        }
    }

    const float cc    = sig_precise(m);
    const float conf  = sig_precise(tc);
    const float score = __fmul_rn(conf, cc);
    const float aw = anc[(6 + a) * 2 + 0] * 0.125f;
    const float ah = anc[(6 + a) * 2 + 1] * 0.125f;
    const float cx = (sig_precise(tx) + (float)(pos % Wd)) / 52.0f;
    const float cy = (sig_precise(ty) + (float)(pos / Wd)) / 52.0f;
    const float bw = expf(tw) * aw / 52.0f;
    const float bh = expf(th) * ah / 52.0f;
    const float hw = __fmul_rn(bw, 0.5f);
    const float hh = __fmul_rn(bh, 0.5f);
    float4* w4 = (float4*)ws;
    w4[2 * n + 0] = make_float4(__fsub_rn(cx, hw), __fsub_rn(cy, hh),
                                __fadd_rn(cx, hw), __fadd_rn(cy, hh));
    w4[2 * n + 1] = make_float4(conf, cc, (float)cp, 0.0f);
    ws[WS_SCORE_OFF + n] = score;
}

// ====== kernel 2 (fused): block 0 = sortless NMS, blocks 1.. = decode ======
__global__ void __launch_bounds__(1024)
yolo_fused(const float* __restrict__ in, const float* __restrict__ anc,
           float* __restrict__ out, const float* __restrict__ ws)
{
    extern __shared__ float dynsm[];
    const int tid = threadIdx.x;

    if (blockIdx.x != 0) {
        // ================= decode (proven conflict-free layout) =================
        const int bi    = (int)blockIdx.x - 1;
        const int chunk = bi % CHUNKS;
        const int ba    = bi / CHUNKS;
        const int a     = ba % An;
        const float anc_w = anc[(6 + a) * 2 + 0] * 0.125f;
        const float anc_h = anc[(6 + a) * 2 + 1] * 0.125f;
        const int pos0  = chunk * CH;
        const float* src = in + (size_t)ba * 85 * HWn + pos0;

        // load+transform: coalesced global, stride-1 LDS writes (conflict-free)
        for (int i = tid; i < ATT * CH; i += 1024) {
            const int attr = i / CH;
            const int p    = i - attr * CH;
            const int pos  = pos0 + p;
            const float x  = src[(size_t)attr * HWn + p];
            float v;
            if (attr >= 4)      v = sig_fast(x);
            else if (attr == 0) v = (sig_fast(x) + (float)(pos % Wd)) / 52.0f;
            else if (attr == 1) v = (sig_fast(x) + (float)(pos / Wd)) / 52.0f;
            else if (attr == 2) v = __expf(x) * anc_w / 52.0f;
            else                v = __expf(x) * anc_h / 52.0f;
            dynsm[attr * PITCH + p] = v;
        }
        __syncthreads();

        // store: contiguous global, LDS stride 209 (bank step 17, conflict-free)
        float* dst = out + ((size_t)ba * HWn + pos0) * ATT;
        for (int f = tid; f < CH * ATT; f += 1024) {
            const int p    = f / ATT;
            const int attr = f - p * ATT;
            dst[f] = dynsm[attr * PITCH + p];
        }
        return;
    }

    // ================= NMS (block 0): sortless argmax-with-suppression =================
    // LDS carve: warr u64[32] (parity x16) | winslot f[8] | detstage f[700]
    unsigned long long* warr = (unsigned long long*)dynsm;
    float* winslot  = dynsm + 64;
    float* detstage = dynsm + 72;

    // register-resident candidates: 8 per thread, slot-major index n = k*1024+tid
    float s[8], qx1[8], qy1[8], qx2[8], qy2[8];
    const float4* w4 = (const float4*)ws;
    const float* wscore = ws + WS_SCORE_OFF;
    #pragma unroll
    for (int k = 0; k < 8; ++k) {
        const int n = k * 1024 + tid;
        if (n < NC) {
            const float sc = wscore[n];
            s[k] = (sc >= 0.5f) ? sc : -1.0f;
            const float4 b0 = w4[2 * n], b1 = w4[2 * n + 1];
            const float off = __fmul_rn(b1.z, 4096.0f);
            qx1[k] = __fadd_rn(b0.x, off);
            qy1[k] = __fadd_rn(b0.y, off);
            qx2[k] = __fadd_rn(b0.z, off);
            qy2[k] = __fadd_rn(b0.w, off);
        } else {
            s[k] = -1.0f;
            qx1[k] = qy1[k] = qx2[k] = qy2[k] = 0.0f;
        }
    }

    int nk = 0;
    for (int pick = 0; pick < 100; ++pick) {
        // local argmax over 8 slots (ascending n, strict > => lowest index on tie)
        float bs = 0.0f; int bn = 0;
        #pragma unroll
        for (int k = 0; k < 8; ++k) {
            if (s[k] > bs) { bs = s[k]; bn = k * 1024 + tid; }
        }
        // pack (score desc, index asc): valid scores in [0.5,1) -> positive bits
        unsigned long long key = (bs > 0.0f)
            ? (((unsigned long long)__float_as_uint(bs) << 32)
               | (unsigned)(0xFFFFFFFFu - (unsigned)bn))
            : 0ULL;
        // wave butterfly max
        #pragma unroll
        for (int o = 1; o < 64; o <<= 1) {
            const unsigned long long other = __shfl_xor(key, o);
            if (other > key) key = other;
        }
        if ((tid & 63) == 0) warr[(pick & 1) * 16 + (tid >> 6)] = key;
        __syncthreads();
        unsigned long long gk = 0ULL;
        #pragma unroll
        for (int w = 0; w < 16; ++w) {
            const unsigned long long other = warr[(pick & 1) * 16 + w];
            if (other > gk) gk = other;
        }
        if (gk == 0ULL) break;                       // no alive candidate (uniform)
        const int nwin = (int)(0xFFFFFFFFu - (unsigned)(gk & 0xFFFFFFFFu));

        if ((nwin & 1023) == tid) {                  // unique owner
            const int slot = nwin >> 10;
            #pragma unroll
            for (int k = 0; k < 8; ++k) {
                if (k == slot) {
                    winslot[0] = qx1[k]; winslot[1] = qy1[k];
                    winslot[2] = qx2[k]; winslot[3] = qy2[k];
                    winslot[4] = __fmul_rn(__fsub_rn(qx2[k], qx1[k]),
                                           __fsub_rn(qy2[k], qy1[k]));
                    s[k] = -1.0f;                    // explicit kill (ref .at[i].set)
                }
            }
            const float4 b0 = w4[2 * nwin], b1 = w4[2 * nwin + 1];
            float* dr = detstage + nk * 7;
            const float xm  = __fmul_rn(__fadd_rn(b0.x, b0.z), 0.5f);
            const float ym  = __fmul_rn(__fadd_rn(b0.y, b0.w), 0.5f);
            const float hw2 = __fmul_rn(__fsub_rn(b0.z, b0.x), 0.5f);
            const float hh2 = __fmul_rn(__fsub_rn(b0.w, b0.y), 0.5f);
            dr[0] = __fmul_rn(__fsub_rn(ym, hh2), 416.0f);
            dr[1] = __fmul_rn(__fsub_rn(xm, hw2), 416.0f);
            dr[2] = __fmul_rn(__fadd_rn(ym, hh2), 416.0f);
            dr[3] = __fmul_rn(__fadd_rn(xm, hw2), 416.0f);
            dr[4] = b1.x; dr[5] = b1.y; dr[6] = b1.z;
        }
        __syncthreads();

        // suppress own 8 candidates vs winner (register-resident, wave-parallel)
        const float wx1 = winslot[0], wy1 = winslot[1];
        const float wx2 = winslot[2], wy2 = winslot[3], aW = winslot[4];
        #pragma unroll
        for (int k = 0; k < 8; ++k) {
            if (s[k] >= 0.0f) {
                const float ltx = fmaxf(wx1, qx1[k]), lty = fmaxf(wy1, qy1[k]);
                const float rbx = fminf(wx2, qx2[k]), rby = fminf(wy2, qy2[k]);
                const float iw = fmaxf(__fsub_rn(rbx, ltx), 0.0f);
                const float ih = fmaxf(__fsub_rn(rby, lty), 0.0f);
                const float inter = __fmul_rn(iw, ih);
                const float aK = __fmul_rn(__fsub_rn(qx2[k], qx1[k]),
                                           __fsub_rn(qy2[k], qy1[k]));
                const float den = __fadd_rn(__fsub_rn(__fadd_rn(aW, aK), inter), 1e-9f);
                if (inter / den > 0.4f) s[k] = -1.0f;
            }
        }
        ++nk;
    }
    __syncthreads();

    // write det (nk uniform): staged rows, zeros for rows >= nk
    for (int i = tid; i < 100 * 7; i += 1024) {
        out[OUT_DEC + i] = (i < nk * 7) ? detstage[i] : 0.0f;
    }
}

extern "C" void kernel_launch(void* const* d_in, const int* in_sizes, int n_in,
                              void* d_out, int out_size, void* d_ws, size_t ws_size,
                              hipStream_t stream) {
    const float* in  = (const float*)d_in[0];
    const float* anc = (const float*)d_in[1];
    float* out = (float*)d_out;
    float* ws  = (float*)d_ws;

    hipLaunchKernelGGL(yolo_prep, dim3((NC + 127) / 128), dim3(128), 0, stream,
                       in, anc, ws);
    hipLaunchKernelGGL(yolo_fused, dim3(DEC_BLOCKS + 1), dim3(1024), DEC_LDS,
                       stream, in, anc, out, ws);
}